// Round 1
// baseline (1046.679 us; speedup 1.0000x reference)
//
#include <hip/hip_runtime.h>

#define HH 480
#define WW 640
#define BB 4
#define PPP 4
#define NN 262144
#define HWPX (HH * WW)

__device__ __forceinline__ float charb6(float a) { return sqrtf(a * a + 1e-6f); }

// ---------------- Event scatter ----------------
__global__ void ev_scatter(const float* __restrict__ ev,
                           const float* __restrict__ pol,
                           const float* __restrict__ ts,
                           float* __restrict__ acc_iwe,
                           float* __restrict__ acc_pts,
                           float* __restrict__ acc_nts) {
    int gid = blockIdx.x * blockDim.x + threadIdx.x;
    if (gid >= BB * NN) return;
    int b = gid / NN;
    int n = gid - b * NN;

    float y = ev[((size_t)b * NN + n) * 2 + 0];
    float x = ev[((size_t)b * NN + n) * 2 + 1];
    float pm0 = pol[((size_t)b * 4 * NN + n) * 2 + 0];
    float pm1 = pol[((size_t)b * 4 * NN + n) * 2 + 1];
    float t = ts[(size_t)b * 4 * NN + n];
    float nt = 1.0f - fabsf(1.0f - t);
    float nt2 = nt * nt;
    float p0 = pm0 * pm0;
    float p1 = pm1 * pm1;

    float y0 = floorf(y);
    float x0 = floorf(x);

    float* iweb = acc_iwe + (size_t)b * HWPX;
    float* ptsb = acc_pts + (size_t)b * HWPX;
    float* ntsb = acc_nts + (size_t)b * HWPX;

#pragma unroll
    for (int c = 0; c < 4; ++c) {
        float cy = y0 + (float)(c >> 1);
        float cx = x0 + (float)(c & 1);
        float wy = fmaxf(0.0f, 1.0f - fabsf(y - cy));
        float wx = fmaxf(0.0f, 1.0f - fabsf(x - cx));
        float wyx = wy * wx;
        bool inb = (cy >= 0.0f) && (cy <= (float)(HH - 1)) &&
                   (cx >= 0.0f) && (cx <= (float)(WW - 1));
        if (!inb || wyx == 0.0f) continue;
        int lin = (int)cy * WW + (int)cx;
        float ci = wyx * (p0 + p1);
        if (ci != 0.0f) atomicAdd(&iweb[lin], ci);
        float wts = wyx * nt2;
        float c0 = wts * p0;
        float c1 = wts * p1;
        if (c0 != 0.0f) atomicAdd(&ptsb[lin], c0);
        if (c1 != 0.0f) atomicAdd(&ntsb[lin], c1);
    }
}

// ---------------- block reduce helper (256 threads) ----------------
__device__ __forceinline__ float block_reduce_256(float v, float* smem) {
#pragma unroll
    for (int off = 32; off > 0; off >>= 1) v += __shfl_down(v, off, 64);
    int lane = threadIdx.x & 63;
    int wid = threadIdx.x >> 6;
    if (lane == 0) smem[wid] = v;
    __syncthreads();
    float r = 0.0f;
    if (threadIdx.x == 0) r = smem[0] + smem[1] + smem[2] + smem[3];
    __syncthreads();
    return r;  // valid only on thread 0
}

// ---------------- Focus loss partial reduction ----------------
__global__ void focus_reduce(const float* __restrict__ acc_iwe,
                             const float* __restrict__ acc_pts,
                             const float* __restrict__ acc_nts,
                             float* __restrict__ ssq,
                             float* __restrict__ cnt) {
    __shared__ float smem[4];
    int b = blockIdx.y;
    int i = blockIdx.x * blockDim.x + threadIdx.x;
    float s = 0.0f, c = 0.0f;
    if (i < HWPX) {
        size_t o = (size_t)b * HWPX + i;
        float p = acc_pts[o];
        float q = acc_nts[o];
        s = p * p + q * q;
        c = (acc_iwe[o] > 0.0f) ? 1.0f : 0.0f;
    }
    float rs = block_reduce_256(s, smem);
    float rc = block_reduce_256(c, smem);
    if (threadIdx.x == 0) {
        atomicAdd(&ssq[b], rs);
        atomicAdd(&cnt[b], rc);
    }
}

// ---------------- Spatial smoothing ----------------
__global__ void spat_kernel(const float* __restrict__ flow, float* __restrict__ spat_acc) {
    __shared__ float smem[4];
    int bp = blockIdx.y;  // b*P + p
    int i = blockIdx.x * blockDim.x + threadIdx.x;
    int h = i / WW;
    int w = i - h * WW;
    const float* fx = flow + ((size_t)bp * 2 + 0) * HWPX;
    const float* fy = flow + ((size_t)bp * 2 + 1) * HWPX;

    const float wdx = 1.0f / ((float)HH * (float)(WW - 1) * (float)PPP * 4.0f);
    const float wdy = 1.0f / ((float)(HH - 1) * (float)WW * (float)PPP * 4.0f);
    const float wdd = 1.0f / ((float)(HH - 1) * (float)(WW - 1) * (float)PPP * 4.0f);

    float acc = 0.0f;
    if (i < HWPX) {
        float fx00 = fx[i];
        float fy00 = fy[i];
        if (w < WW - 1) {
            acc += wdx * (charb6(fx00 - fx[i + 1]) + charb6(fy00 - fy[i + 1]));
        }
        if (h < HH - 1) {
            acc += wdy * (charb6(fx00 - fx[i + WW]) + charb6(fy00 - fy[i + WW]));
            if (w < WW - 1) {
                acc += wdd * (charb6(fx00 - fx[i + WW + 1]) + charb6(fy00 - fy[i + WW + 1]));
                acc += wdd * (charb6(fx[i + WW] - fx[i + 1]) + charb6(fy[i + WW] - fy[i + 1]));
            }
        }
    }
    float r = block_reduce_256(acc, smem);
    if (threadIdx.x == 0) atomicAdd(spat_acc, r);
}

// ---------------- Temporal smoothing ----------------
__global__ void temp_kernel(const float* __restrict__ flow,
                            float* __restrict__ sum_dt,
                            float* __restrict__ sum_mask) {
    __shared__ float smem[4];
    int bp = blockIdx.y;  // b*(P-1) + p
    int b = bp / (PPP - 1);
    int p = bp - b * (PPP - 1);
    int i = blockIdx.x * blockDim.x + threadIdx.x;
    int h = i / WW;
    int w = i - h * WW;

    const float* fx_c = flow + (((size_t)b * PPP + p) * 2 + 0) * HWPX;
    const float* fy_c = flow + (((size_t)b * PPP + p) * 2 + 1) * HWPX;
    const float* fx_n = flow + (((size_t)b * PPP + p + 1) * 2 + 0) * HWPX;
    const float* fy_n = flow + (((size_t)b * PPP + p + 1) * 2 + 1) * HWPX;

    float m = 0.0f, dt = 0.0f;
    if (i < HWPX) {
        float cy = fy_c[i];
        float cx = fx_c[i];
        float wy = (float)h + cy;
        float wx = (float)w + cx;
        bool inb = (wy >= 0.0f) && (wy <= (float)(HH - 1)) &&
                   (wx >= 0.0f) && (wx <= (float)(WW - 1));
        m = inb ? 1.0f : 0.0f;
        if (inb) {
            float y0f = floorf(wy);
            float x0f = floorf(wx);
            float wy1 = wy - y0f, wy0 = 1.0f - wy1;
            float wx1 = wx - x0f, wx0 = 1.0f - wx1;
            int y0i = (int)fminf(fmaxf(y0f, 0.0f), (float)(HH - 1));
            int y1i = (int)fminf(fmaxf(y0f + 1.0f, 0.0f), (float)(HH - 1));
            int x0i = (int)fminf(fmaxf(x0f, 0.0f), (float)(WW - 1));
            int x1i = (int)fminf(fmaxf(x0f + 1.0f, 0.0f), (float)(WW - 1));
            float w00 = wy0 * wx0, w01 = wy0 * wx1, w10 = wy1 * wx0, w11 = wy1 * wx1;
            float wfy = w00 * fy_n[y0i * WW + x0i] + w01 * fy_n[y0i * WW + x1i] +
                        w10 * fy_n[y1i * WW + x0i] + w11 * fy_n[y1i * WW + x1i];
            float wfx = w00 * fx_n[y0i * WW + x0i] + w01 * fx_n[y0i * WW + x1i] +
                        w10 * fx_n[y1i * WW + x0i] + w11 * fx_n[y1i * WW + x1i];
            float dy = cy - wfy;
            float dx = cx - wfx;
            dt = sqrtf(dy * dy + 1e-9f) + sqrtf(dx * dx + 1e-9f);
        }
    }
    float rd = block_reduce_256(dt, smem);
    float rm = block_reduce_256(m, smem);
    if (threadIdx.x == 0) {
        atomicAdd(&sum_dt[bp], rd);
        atomicAdd(&sum_mask[bp], rm);
    }
}

// ---------------- Finalize ----------------
__global__ void finalize_kernel(const float* __restrict__ ssq,
                                const float* __restrict__ cnt,
                                const float* __restrict__ spat,
                                const float* __restrict__ sdt,
                                const float* __restrict__ smask,
                                float* __restrict__ out) {
    float loss = 0.0f;
    for (int b = 0; b < BB; ++b) loss += ssq[b] / (cnt[b] + 1e-9f);
    loss += 1.0f /*FLOW_SPAT_W*/ * spat[0];
    float tl = 0.0f;
    for (int b = 0; b < BB; ++b) {
        float s = 0.0f;
        for (int p = 0; p < PPP - 1; ++p) {
            int bp = b * (PPP - 1) + p;
            s += sdt[bp] / (smask[bp] + 1e-9f);
        }
        tl += s / (float)(PPP - 1);
    }
    loss += 1.0f /*FLOW_TEMP_W*/ * tl;
    out[0] = loss;
}

extern "C" void kernel_launch(void* const* d_in, const int* in_sizes, int n_in,
                              void* d_out, int out_size, void* d_ws, size_t ws_size,
                              hipStream_t stream) {
    const float* ev   = (const float*)d_in[0];  // (B,N,2)
    const float* pol  = (const float*)d_in[1];  // (B,4N,2)
    const float* ts   = (const float*)d_in[2];  // (B,4N,1)
    const float* flow = (const float*)d_in[3];  // (B,P,2,H,W)
    float* out = (float*)d_out;
    float* ws = (float*)d_ws;

    const size_t img = (size_t)BB * HWPX;
    float* acc_iwe = ws;
    float* acc_pts = ws + img;
    float* acc_nts = ws + 2 * img;
    float* ssq  = ws + 3 * img;          // B
    float* cnt  = ssq + BB;              // B
    float* spat = cnt + BB;              // 1
    float* sdt  = spat + 1;              // B*(P-1)
    float* smsk = sdt + BB * (PPP - 1);  // B*(P-1)

    size_t zbytes = (3 * img + 2 * BB + 1 + 2 * BB * (PPP - 1)) * sizeof(float);
    hipMemsetAsync(d_ws, 0, zbytes, stream);

    int evThreads = BB * NN;
    ev_scatter<<<(evThreads + 255) / 256, 256, 0, stream>>>(ev, pol, ts, acc_iwe, acc_pts, acc_nts);

    dim3 gFocus((HWPX + 255) / 256, BB);
    focus_reduce<<<gFocus, 256, 0, stream>>>(acc_iwe, acc_pts, acc_nts, ssq, cnt);

    dim3 gSpat((HWPX + 255) / 256, BB * PPP);
    spat_kernel<<<gSpat, 256, 0, stream>>>(flow, spat);

    dim3 gTemp((HWPX + 255) / 256, BB * (PPP - 1));
    temp_kernel<<<gTemp, 256, 0, stream>>>(flow, sdt, smsk);

    finalize_kernel<<<1, 1, 0, stream>>>(ssq, cnt, spat, sdt, smsk, out);
}

// Round 2
// 599.333 us; speedup vs baseline: 1.7464x; 1.7464x over previous
//
#include <hip/hip_runtime.h>

#define HH 480
#define WW 640
#define BB 4
#define PPP 4
#define NN 262144
#define HWPX (HH * WW)
#define NBX 1200  // HWPX / 256

__device__ __forceinline__ float charb6(float a) { return sqrtf(a * a + 1e-6f); }

// ---------------- block reduce helper (256 threads) ----------------
__device__ __forceinline__ float block_reduce_256(float v, float* smem) {
#pragma unroll
    for (int off = 32; off > 0; off >>= 1) v += __shfl_down(v, off, 64);
    int lane = threadIdx.x & 63;
    int wid = threadIdx.x >> 6;
    if (lane == 0) smem[wid] = v;
    __syncthreads();
    float r = 0.0f;
    if (threadIdx.x == 0) r = smem[0] + smem[1] + smem[2] + smem[3];
    __syncthreads();
    return r;  // valid only on thread 0
}

// ---------------- Event scatter into per-XCD replicas ----------------
// reps layout: [r][b][pol][pix], r in [0,R)
template <int LOCAL>
__global__ void ev_scatter_rep(const float* __restrict__ ev,
                               const float* __restrict__ pol,
                               const float* __restrict__ ts,
                               float* __restrict__ reps) {
    int gid = blockIdx.x * 256 + threadIdx.x;  // exactly B*N threads
    int b = gid >> 18;                         // N = 2^18
    int n = gid & (NN - 1);

    unsigned xcc = 0;
    if (LOCAL) {
        asm volatile("s_getreg_b32 %0, hwreg(HW_REG_XCC_ID)" : "=s"(xcc));
        xcc &= 7;
    }

    float2 yx = ((const float2*)ev)[(size_t)b * NN + n];
    float p0 = pol[((size_t)b * 4 * NN + n) * 2];
    float t = ts[(size_t)b * 4 * NN + n];
    float nt = 1.0f - fabsf(1.0f - t);
    float nt2 = nt * nt;
    float y = yx.x, x = yx.y;
    float y0 = floorf(y), x0 = floorf(x);

    float* base = reps + (((size_t)xcc * BB + b) * 2 + (p0 > 0.5f ? 0 : 1)) * HWPX;

#pragma unroll
    for (int c = 0; c < 4; ++c) {
        float cy = y0 + (float)(c >> 1);
        float cx = x0 + (float)(c & 1);
        float wy = fmaxf(0.0f, 1.0f - fabsf(y - cy));
        float wx = fmaxf(0.0f, 1.0f - fabsf(x - cx));
        float v = wy * wx * nt2;
        bool inb = (cy >= 0.0f) && (cy <= (float)(HH - 1)) &&
                   (cx >= 0.0f) && (cx <= (float)(WW - 1));
        if (!inb || v == 0.0f) continue;
        int lin = (int)cy * WW + (int)cx;
        if (LOCAL)
            __hip_atomic_fetch_add(base + lin, v, __ATOMIC_RELAXED, __HIP_MEMORY_SCOPE_WORKGROUP);
        else
            atomicAdd(base + lin, v);
    }
}

// ---------------- Fused reduce: focus (y<4), spat (4<=y<20), temp (20<=y<32) ----
__global__ void fused_reduce(const float* __restrict__ reps, int R,
                             const float* __restrict__ flow,
                             float* __restrict__ P1, float* __restrict__ P2) {
    __shared__ float smem[4];
    int y = blockIdx.y;
    int i = blockIdx.x * 256 + threadIdx.x;  // pixel, < HWPX exactly
    int h = i / WW;
    int w = i - h * WW;

    float a1 = 0.0f, a2 = 0.0f;

    if (y < 4) {
        // ---- focus: sum replicas, square, count nonzero ----
        int b = y;
        float ps = 0.0f, ns = 0.0f;
        for (int r = 0; r < R; ++r) {
            const float* rb = reps + (((size_t)r * BB + b) * 2) * HWPX;
            ps += rb[i];
            ns += rb[HWPX + i];
        }
        a1 = ps * ps + ns * ns;
        a2 = (ps > 0.0f || ns > 0.0f) ? 1.0f : 0.0f;
    } else if (y < 20) {
        // ---- spatial smoothing, bp = y-4 ----
        int bp = y - 4;
        const float* fx = flow + ((size_t)bp * 2 + 0) * HWPX;
        const float* fy = flow + ((size_t)bp * 2 + 1) * HWPX;
        const float wdx = 1.0f / ((float)HH * (float)(WW - 1) * (float)PPP * 4.0f);
        const float wdy = 1.0f / ((float)(HH - 1) * (float)WW * (float)PPP * 4.0f);
        const float wdd = 1.0f / ((float)(HH - 1) * (float)(WW - 1) * (float)PPP * 4.0f);

        float fx00 = fx[i];
        float fy00 = fy[i];
        if (w < WW - 1) {
            a1 += wdx * (charb6(fx00 - fx[i + 1]) + charb6(fy00 - fy[i + 1]));
        }
        if (h < HH - 1) {
            a1 += wdy * (charb6(fx00 - fx[i + WW]) + charb6(fy00 - fy[i + WW]));
            if (w < WW - 1) {
                a1 += wdd * (charb6(fx00 - fx[i + WW + 1]) + charb6(fy00 - fy[i + WW + 1]));
                a1 += wdd * (charb6(fx[i + WW] - fx[i + 1]) + charb6(fy[i + WW] - fy[i + 1]));
            }
        }
    } else {
        // ---- temporal smoothing, bp = y-20 ----
        int bp = y - 20;
        int b = bp / (PPP - 1);
        int p = bp - b * (PPP - 1);
        const float* fx_c = flow + (((size_t)b * PPP + p) * 2 + 0) * HWPX;
        const float* fy_c = flow + (((size_t)b * PPP + p) * 2 + 1) * HWPX;
        const float* fx_n = flow + (((size_t)b * PPP + p + 1) * 2 + 0) * HWPX;
        const float* fy_n = flow + (((size_t)b * PPP + p + 1) * 2 + 1) * HWPX;

        float cy = fy_c[i];
        float cx = fx_c[i];
        float wy = (float)h + cy;
        float wx = (float)w + cx;
        bool inb = (wy >= 0.0f) && (wy <= (float)(HH - 1)) &&
                   (wx >= 0.0f) && (wx <= (float)(WW - 1));
        a2 = inb ? 1.0f : 0.0f;
        if (inb) {
            float y0f = floorf(wy);
            float x0f = floorf(wx);
            float wy1 = wy - y0f, wy0 = 1.0f - wy1;
            float wx1 = wx - x0f, wx0 = 1.0f - wx1;
            int y0i = (int)fminf(fmaxf(y0f, 0.0f), (float)(HH - 1));
            int y1i = (int)fminf(fmaxf(y0f + 1.0f, 0.0f), (float)(HH - 1));
            int x0i = (int)fminf(fmaxf(x0f, 0.0f), (float)(WW - 1));
            int x1i = (int)fminf(fmaxf(x0f + 1.0f, 0.0f), (float)(WW - 1));
            float w00 = wy0 * wx0, w01 = wy0 * wx1, w10 = wy1 * wx0, w11 = wy1 * wx1;
            float wfy = w00 * fy_n[y0i * WW + x0i] + w01 * fy_n[y0i * WW + x1i] +
                        w10 * fy_n[y1i * WW + x0i] + w11 * fy_n[y1i * WW + x1i];
            float wfx = w00 * fx_n[y0i * WW + x0i] + w01 * fx_n[y0i * WW + x1i] +
                        w10 * fx_n[y1i * WW + x0i] + w11 * fx_n[y1i * WW + x1i];
            float dy = cy - wfy;
            float dx = cx - wfx;
            a1 = sqrtf(dy * dy + 1e-9f) + sqrtf(dx * dx + 1e-9f);
        }
    }

    float r1 = block_reduce_256(a1, smem);
    float r2 = block_reduce_256(a2, smem);
    if (threadIdx.x == 0) {
        P1[y * NBX + blockIdx.x] = r1;
        P2[y * NBX + blockIdx.x] = r2;
    }
}

// ---------------- Finalize: one wave sums the partials ----------------
__global__ void finalize_kernel(const float* __restrict__ P1,
                                const float* __restrict__ P2,
                                float* __restrict__ out) {
    __shared__ float rowsum[64];
    int t = threadIdx.x;  // 64 threads
    for (int row = 0; row < 64; ++row) {
        const float* src = (row < 32) ? (P1 + row * NBX) : (P2 + (row - 32) * NBX);
        float v = 0.0f;
        for (int i = t; i < NBX; i += 64) v += src[i];
#pragma unroll
        for (int off = 32; off > 0; off >>= 1) v += __shfl_down(v, off, 64);
        if (t == 0) rowsum[row] = v;
    }
    if (t == 0) {
        float loss = 0.0f;
        for (int b = 0; b < 4; ++b) loss += rowsum[b] / (rowsum[32 + b] + 1e-9f);
        for (int r = 4; r < 20; ++r) loss += rowsum[r];
        float tl = 0.0f;
        for (int r = 20; r < 32; ++r) tl += rowsum[r] / (rowsum[32 + r] + 1e-9f);
        loss += tl / (float)(PPP - 1);
        out[0] = loss;
    }
}

extern "C" void kernel_launch(void* const* d_in, const int* in_sizes, int n_in,
                              void* d_out, int out_size, void* d_ws, size_t ws_size,
                              hipStream_t stream) {
    const float* ev = (const float*)d_in[0];    // (B,N,2)
    const float* pol = (const float*)d_in[1];   // (B,4N,2)
    const float* ts = (const float*)d_in[2];    // (B,4N,1)
    const float* flow = (const float*)d_in[3];  // (B,P,2,H,W)
    float* out = (float*)d_out;
    float* ws = (float*)d_ws;

    const size_t per_rep = (size_t)BB * 2 * HWPX;  // floats per replica set
    const size_t partials = (size_t)64 * NBX;      // P1 + P2
    int R = ((8 * per_rep + partials) * sizeof(float) <= ws_size) ? 8 : 1;

    float* reps = ws;
    float* P1 = ws + (size_t)R * per_rep;
    float* P2 = P1 + 32 * NBX;

    hipMemsetAsync(d_ws, 0, (size_t)R * per_rep * sizeof(float), stream);

    if (R == 8)
        ev_scatter_rep<1><<<(BB * NN) / 256, 256, 0, stream>>>(ev, pol, ts, reps);
    else
        ev_scatter_rep<0><<<(BB * NN) / 256, 256, 0, stream>>>(ev, pol, ts, reps);

    dim3 gR(NBX, 32);
    fused_reduce<<<gR, 256, 0, stream>>>(reps, R, flow, P1, P2);

    finalize_kernel<<<1, 64, 0, stream>>>(P1, P2, out);
}

// Round 3
// 313.985 us; speedup vs baseline: 3.3335x; 1.9088x over previous
//
#include <hip/hip_runtime.h>

#define HH 480
#define WW 640
#define BB 4
#define PPP 4
#define NN 262144
#define HWPX (HH * WW)
#define NB2 150  // blocks per reduce row; each block strides 8 chunks of 256

__device__ __forceinline__ float charb6(float a) { return sqrtf(a * a + 1e-6f); }

// ---------------- block reduce helper (256 threads) ----------------
__device__ __forceinline__ float block_reduce_256(float v, float* smem) {
#pragma unroll
    for (int off = 32; off > 0; off >>= 1) v += __shfl_down(v, off, 64);
    int lane = threadIdx.x & 63;
    int wid = threadIdx.x >> 6;
    if (lane == 0) smem[wid] = v;
    __syncthreads();
    float r = 0.0f;
    if (threadIdx.x == 0) r = smem[0] + smem[1] + smem[2] + smem[3];
    __syncthreads();
    return r;  // valid only on thread 0
}

// ---------------- Event scatter into per-XCD replicas ----------------
// reps layout: [r][b][pol][pix], r in [0,R)
template <int LOCAL>
__global__ void ev_scatter_rep(const float* __restrict__ ev,
                               const float* __restrict__ pol,
                               const float* __restrict__ ts,
                               float* __restrict__ reps) {
    int gid = blockIdx.x * 256 + threadIdx.x;  // exactly B*N threads
    int b = gid >> 18;                         // N = 2^18
    int n = gid & (NN - 1);

    unsigned xcc = 0;
    if (LOCAL) {
        asm volatile("s_getreg_b32 %0, hwreg(HW_REG_XCC_ID)" : "=s"(xcc));
        xcc &= 7;
    }

    float2 yx = ((const float2*)ev)[(size_t)b * NN + n];
    float p0 = pol[((size_t)b * 4 * NN + n) * 2];
    float t = ts[(size_t)b * 4 * NN + n];
    float nt = 1.0f - fabsf(1.0f - t);
    float nt2 = nt * nt;
    float y = yx.x, x = yx.y;
    float y0 = floorf(y), x0 = floorf(x);

    float* base = reps + (((size_t)xcc * BB + b) * 2 + (p0 > 0.5f ? 0 : 1)) * HWPX;

#pragma unroll
    for (int c = 0; c < 4; ++c) {
        float cy = y0 + (float)(c >> 1);
        float cx = x0 + (float)(c & 1);
        float wy = fmaxf(0.0f, 1.0f - fabsf(y - cy));
        float wx = fmaxf(0.0f, 1.0f - fabsf(x - cx));
        float v = wy * wx * nt2;
        bool inb = (cy >= 0.0f) && (cy <= (float)(HH - 1)) &&
                   (cx >= 0.0f) && (cx <= (float)(WW - 1));
        if (!inb || v == 0.0f) continue;
        int lin = (int)cy * WW + (int)cx;
        if (LOCAL)
            __hip_atomic_fetch_add(base + lin, v, __ATOMIC_RELAXED, __HIP_MEMORY_SCOPE_WORKGROUP);
        else
            atomicAdd(base + lin, v);
    }
}

// ---------------- Fused reduce: focus (y<4), spat (4<=y<20), temp (20<=y<32) ----
// Each block covers 8 chunks of 256 pixels (grid-stride). Results go straight
// into acc[64] via device atomics (~NB2 adds per slot).
__global__ void fused_reduce(const float* __restrict__ reps, int R,
                             const float* __restrict__ flow,
                             float* __restrict__ acc) {
    __shared__ float smem[4];
    int y = blockIdx.y;
    float a1 = 0.0f, a2 = 0.0f;

    for (int k = 0; k < 8; ++k) {
        int i = (blockIdx.x + k * NB2) * 256 + threadIdx.x;  // < HWPX exactly
        int h = i / WW;
        int w = i - h * WW;

        if (y < 4) {
            // ---- focus: sum replicas, square, count nonzero ----
            int b = y;
            float ps = 0.0f, ns = 0.0f;
            for (int r = 0; r < R; ++r) {
                const float* rb = reps + (((size_t)r * BB + b) * 2) * HWPX;
                ps += rb[i];
                ns += rb[HWPX + i];
            }
            a1 += ps * ps + ns * ns;
            a2 += (ps > 0.0f || ns > 0.0f) ? 1.0f : 0.0f;
        } else if (y < 20) {
            // ---- spatial smoothing, bp = y-4 ----
            int bp = y - 4;
            const float* fx = flow + ((size_t)bp * 2 + 0) * HWPX;
            const float* fy = flow + ((size_t)bp * 2 + 1) * HWPX;
            const float wdx = 1.0f / ((float)HH * (float)(WW - 1) * (float)PPP * 4.0f);
            const float wdy = 1.0f / ((float)(HH - 1) * (float)WW * (float)PPP * 4.0f);
            const float wdd = 1.0f / ((float)(HH - 1) * (float)(WW - 1) * (float)PPP * 4.0f);

            float fx00 = fx[i];
            float fy00 = fy[i];
            if (w < WW - 1) {
                a1 += wdx * (charb6(fx00 - fx[i + 1]) + charb6(fy00 - fy[i + 1]));
            }
            if (h < HH - 1) {
                a1 += wdy * (charb6(fx00 - fx[i + WW]) + charb6(fy00 - fy[i + WW]));
                if (w < WW - 1) {
                    a1 += wdd * (charb6(fx00 - fx[i + WW + 1]) + charb6(fy00 - fy[i + WW + 1]));
                    a1 += wdd * (charb6(fx[i + WW] - fx[i + 1]) + charb6(fy[i + WW] - fy[i + 1]));
                }
            }
        } else {
            // ---- temporal smoothing, bp = y-20 ----
            int bp = y - 20;
            int b = bp / (PPP - 1);
            int p = bp - b * (PPP - 1);
            const float* fx_c = flow + (((size_t)b * PPP + p) * 2 + 0) * HWPX;
            const float* fy_c = flow + (((size_t)b * PPP + p) * 2 + 1) * HWPX;
            const float* fx_n = flow + (((size_t)b * PPP + p + 1) * 2 + 0) * HWPX;
            const float* fy_n = flow + (((size_t)b * PPP + p + 1) * 2 + 1) * HWPX;

            float cy = fy_c[i];
            float cx = fx_c[i];
            float wy = (float)h + cy;
            float wx = (float)w + cx;
            bool inb = (wy >= 0.0f) && (wy <= (float)(HH - 1)) &&
                       (wx >= 0.0f) && (wx <= (float)(WW - 1));
            a2 += inb ? 1.0f : 0.0f;
            if (inb) {
                float y0f = floorf(wy);
                float x0f = floorf(wx);
                float wy1 = wy - y0f, wy0 = 1.0f - wy1;
                float wx1 = wx - x0f, wx0 = 1.0f - wx1;
                int y0i = (int)fminf(fmaxf(y0f, 0.0f), (float)(HH - 1));
                int y1i = (int)fminf(fmaxf(y0f + 1.0f, 0.0f), (float)(HH - 1));
                int x0i = (int)fminf(fmaxf(x0f, 0.0f), (float)(WW - 1));
                int x1i = (int)fminf(fmaxf(x0f + 1.0f, 0.0f), (float)(WW - 1));
                float w00 = wy0 * wx0, w01 = wy0 * wx1, w10 = wy1 * wx0, w11 = wy1 * wx1;
                float wfy = w00 * fy_n[y0i * WW + x0i] + w01 * fy_n[y0i * WW + x1i] +
                            w10 * fy_n[y1i * WW + x0i] + w11 * fy_n[y1i * WW + x1i];
                float wfx = w00 * fx_n[y0i * WW + x0i] + w01 * fx_n[y0i * WW + x1i] +
                            w10 * fx_n[y1i * WW + x0i] + w11 * fx_n[y1i * WW + x1i];
                float dy = cy - wfy;
                float dx = cx - wfx;
                a1 += sqrtf(dy * dy + 1e-9f) + sqrtf(dx * dx + 1e-9f);
            }
        }
    }

    float r1 = block_reduce_256(a1, smem);
    float r2 = block_reduce_256(a2, smem);
    if (threadIdx.x == 0) {
        atomicAdd(&acc[y], r1);
        atomicAdd(&acc[32 + y], r2);
    }
}

// ---------------- Finalize: read 64 scalars ----------------
__global__ void finalize_kernel(const float* __restrict__ acc,
                                float* __restrict__ out) {
    if (threadIdx.x == 0) {
        float loss = 0.0f;
        for (int b = 0; b < BB; ++b) loss += acc[b] / (acc[32 + b] + 1e-9f);
        for (int r = 4; r < 20; ++r) loss += acc[r];
        float tl = 0.0f;
        for (int r = 20; r < 32; ++r) tl += acc[r] / (acc[32 + r] + 1e-9f);
        loss += tl / (float)(PPP - 1);
        out[0] = loss;
    }
}

extern "C" void kernel_launch(void* const* d_in, const int* in_sizes, int n_in,
                              void* d_out, int out_size, void* d_ws, size_t ws_size,
                              hipStream_t stream) {
    const float* ev = (const float*)d_in[0];    // (B,N,2)
    const float* pol = (const float*)d_in[1];   // (B,4N,2)
    const float* ts = (const float*)d_in[2];    // (B,4N,1)
    const float* flow = (const float*)d_in[3];  // (B,P,2,H,W)
    float* out = (float*)d_out;
    float* ws = (float*)d_ws;

    const size_t per_rep = (size_t)BB * 2 * HWPX;  // floats per replica set
    int R = ((8 * per_rep + 64) * sizeof(float) <= ws_size) ? 8 : 1;

    float* reps = ws;
    float* acc = ws + (size_t)R * per_rep;  // 64 floats

    hipMemsetAsync(d_ws, 0, ((size_t)R * per_rep + 64) * sizeof(float), stream);

    if (R == 8)
        ev_scatter_rep<1><<<(BB * NN) / 256, 256, 0, stream>>>(ev, pol, ts, reps);
    else
        ev_scatter_rep<0><<<(BB * NN) / 256, 256, 0, stream>>>(ev, pol, ts, reps);

    dim3 gR(NB2, 32);
    fused_reduce<<<gR, 256, 0, stream>>>(reps, R, flow, acc);

    finalize_kernel<<<1, 64, 0, stream>>>(acc, out);
}